// Round 1
// baseline (598.552 us; speedup 1.0000x reference)
//
#include <hip/hip_runtime.h>

#define NN 10000
#define NE 640000
#define CH 128
#define NH 8
#define HD 16
#define BD 32
#define NEG 0.01f
#define EPB 32   // edges per block in edge kernel

// ---------------- node projections: Q = recv@WQ, K = send@WK, V = send@WV ----
__global__ __launch_bounds__(128) void proj_kernel(
    const float* __restrict__ senders, const float* __restrict__ receivers,
    const float* __restrict__ WQ, const float* __restrict__ WK,
    const float* __restrict__ WV,
    float* __restrict__ Qn, float* __restrict__ Kn, float* __restrict__ Vn)
{
    int n = blockIdx.x;
    int c = threadIdx.x;
    __shared__ float rs[CH], ss[CH];
    rs[c] = receivers[n * CH + c];
    ss[c] = senders[n * CH + c];
    __syncthreads();
    float q = 0.f, k = 0.f, v = 0.f;
#pragma unroll 4
    for (int kk = 0; kk < CH; ++kk) {
        float r = rs[kk], s = ss[kk];
        q = fmaf(r, WQ[kk * CH + c], q);
        k = fmaf(s, WK[kk * CH + c], k);
        v = fmaf(s, WV[kk * CH + c], v);
    }
    Qn[n * CH + c] = q;
    Kn[n * CH + c] = k;
    Vn[n * CH + c] = v;
}

// ---------------- per-edge: E-proj + leaky + per-head logits -> exp ----------
__global__ __launch_bounds__(128) void edge_kernel(
    const int* __restrict__ eidx, const float* __restrict__ eattr,
    const float* __restrict__ WE, const float* __restrict__ att,
    const float* __restrict__ Qn, const float* __restrict__ Kn,
    float* __restrict__ ex)
{
    __shared__ float sWE[BD * CH];    // 16 KB
    __shared__ float sea[EPB * BD];   // 4 KB
    __shared__ int s_src[EPB], s_dst[EPB];
    int tid = threadIdx.x;
    int e0 = blockIdx.x * EPB;
    for (int i = tid; i < BD * CH; i += 128) sWE[i] = WE[i];
    for (int i = tid; i < EPB * BD; i += 128) sea[i] = eattr[(size_t)e0 * BD + i];
    if (tid < EPB) {
        s_src[tid] = eidx[e0 + tid];
        s_dst[tid] = eidx[NE + e0 + tid];
    }
    __syncthreads();
    float a = att[tid];          // attention flat [H*HD] == [128]
    int c = tid;
    int h = c >> 4;
    for (int e = 0; e < EPB; ++e) {
        int src = s_src[e], dst = s_dst[e];
        float ec = 0.f;
#pragma unroll
        for (int k = 0; k < BD; ++k)
            ec = fmaf(sea[e * BD + k], sWE[k * CH + c], ec);
        float val = Qn[dst * CH + c] + Kn[src * CH + c] + ec;
        val = val > 0.f ? val : NEG * val;
        float t = a * val;
        t += __shfl_down(t, 8, 16);
        t += __shfl_down(t, 4, 16);
        t += __shfl_down(t, 2, 16);
        t += __shfl_down(t, 1, 16);
        if ((c & 15) == 0) ex[(size_t)(e0 + e) * NH + h] = __expf(t);
    }
}

// ---------------- counting sort of edges by dst ------------------------------
__global__ void zero_counts(int* __restrict__ counts)
{
    int i = blockIdx.x * blockDim.x + threadIdx.x;
    if (i < NN) counts[i] = 0;
}

__global__ void hist_kernel(const int* __restrict__ eidx, int* __restrict__ counts)
{
    int e = blockIdx.x * blockDim.x + threadIdx.x;
    if (e < NE) atomicAdd(&counts[eidx[NE + e]], 1);
}

__global__ __launch_bounds__(256) void scan_kernel(
    const int* __restrict__ counts, int* __restrict__ starts, int* __restrict__ cursor)
{
    __shared__ int s[256];
    int tid = threadIdx.x;
    const int CHUNK = (NN + 255) / 256;  // 40
    int base = tid * CHUNK;
    int local = 0;
    for (int i = base; i < base + CHUNK && i < NN; ++i) local += counts[i];
    s[tid] = local;
    __syncthreads();
    for (int off = 1; off < 256; off <<= 1) {
        int t = (tid >= off) ? s[tid - off] : 0;
        __syncthreads();
        s[tid] += t;
        __syncthreads();
    }
    int run = s[tid] - local;  // exclusive prefix for this chunk
    for (int i = base; i < base + CHUNK && i < NN; ++i) {
        starts[i] = run;
        cursor[i] = run;
        run += counts[i];
    }
    if (tid == 255) starts[NN] = s[255];
}

__global__ void scatter_kernel(const int* __restrict__ eidx,
                               int* __restrict__ cursor, int* __restrict__ perm)
{
    int e = blockIdx.x * blockDim.x + threadIdx.x;
    if (e < NE) {
        int p = atomicAdd(&cursor[eidx[NE + e]], 1);
        perm[p] = e;
    }
}

// ---------------- per-node segment softmax + weighted V accumulate ----------
#define TILE 128
__global__ __launch_bounds__(128) void agg_kernel(
    const int* __restrict__ eidx, const int* __restrict__ perm,
    const int* __restrict__ starts, const float* __restrict__ ex,
    const float* __restrict__ Vn, float* __restrict__ out)
{
    int n = blockIdx.x;
    int c = threadIdx.x;
    int h = c >> 4;
    int start = starts[n], end = starts[n + 1];
    __shared__ int s_e[TILE], s_src[TILE];
    float acc = 0.f, sume = 0.f;
    for (int base = start; base < end; base += TILE) {
        int m = min(TILE, end - base);
        __syncthreads();
        if (c < m) {
            int e = perm[base + c];
            s_e[c] = e;
            s_src[c] = eidx[e];
        }
        __syncthreads();
        for (int j = 0; j < m; ++j) {
            int e = s_e[j], src = s_src[j];
            float exv = ex[(size_t)e * NH + h];
            sume += exv;
            acc = fmaf(exv, Vn[src * CH + c], acc);
        }
    }
    out[n * CH + c] = (end > start) ? acc / sume : 0.f;
}

extern "C" void kernel_launch(void* const* d_in, const int* in_sizes, int n_in,
                              void* d_out, int out_size, void* d_ws, size_t ws_size,
                              hipStream_t stream)
{
    const float* senders   = (const float*)d_in[0];
    const float* receivers = (const float*)d_in[1];
    const int*   eidx      = (const int*)d_in[2];
    const float* eattr     = (const float*)d_in[3];
    const float* WQ  = (const float*)d_in[4];
    const float* WK  = (const float*)d_in[5];
    const float* WV  = (const float*)d_in[6];
    const float* WE  = (const float*)d_in[7];
    const float* att = (const float*)d_in[8];
    float* out = (float*)d_out;

    char* ws = (char*)d_ws;
    size_t off = 0;
    auto alloc = [&](size_t bytes) -> void* {
        void* p = ws + off;
        off += (bytes + 255) & ~(size_t)255;
        return p;
    };
    float* Qn     = (float*)alloc((size_t)NN * CH * 4);
    float* Kn     = (float*)alloc((size_t)NN * CH * 4);
    float* Vn     = (float*)alloc((size_t)NN * CH * 4);
    float* ex     = (float*)alloc((size_t)NE * NH * 4);
    int*   counts = (int*)alloc((size_t)NN * 4);
    int*   starts = (int*)alloc((size_t)(NN + 1) * 4);
    int*   cursor = (int*)alloc((size_t)NN * 4);
    int*   perm   = (int*)alloc((size_t)NE * 4);

    proj_kernel<<<NN, 128, 0, stream>>>(senders, receivers, WQ, WK, WV, Qn, Kn, Vn);
    edge_kernel<<<NE / EPB, 128, 0, stream>>>(eidx, eattr, WE, att, Qn, Kn, ex);
    zero_counts<<<(NN + 255) / 256, 256, 0, stream>>>(counts);
    hist_kernel<<<(NE + 255) / 256, 256, 0, stream>>>(eidx, counts);
    scan_kernel<<<1, 256, 0, stream>>>(counts, starts, cursor);
    scatter_kernel<<<(NE + 255) / 256, 256, 0, stream>>>(eidx, cursor, perm);
    agg_kernel<<<NN, 128, 0, stream>>>(eidx, perm, starts, ex, Vn, out);
}

// Round 3
// 517.576 us; speedup vs baseline: 1.1565x; 1.1565x over previous
//
#include <hip/hip_runtime.h>

#define NN 10000
#define NE 640000
#define CH 128
#define NH 8
#define HD 16
#define BD 32
#define NEG 0.01f
#define NPB 8     // nodes per block in proj kernel
#define ET 32     // edge tile in fused kernel

// ---------------- node projections: Q = recv@WQ, K = send@WK, V = send@WV ----
// 8 nodes/block so each W element fetched from L2 is reused 8x.
__global__ __launch_bounds__(128) void proj_kernel(
    const float* __restrict__ senders, const float* __restrict__ receivers,
    const float* __restrict__ WQ, const float* __restrict__ WK,
    const float* __restrict__ WV,
    float* __restrict__ Qn, float* __restrict__ Kn, float* __restrict__ Vn)
{
    int nb = blockIdx.x * NPB;   // 10000 % 8 == 0
    int c = threadIdx.x;
    __shared__ float rs[NPB * CH], ss[NPB * CH];
#pragma unroll
    for (int i = 0; i < NPB; ++i) {
        rs[i * CH + c] = receivers[(size_t)(nb + i) * CH + c];
        ss[i * CH + c] = senders[(size_t)(nb + i) * CH + c];
    }
    __syncthreads();
    float q[NPB], k[NPB], v[NPB];
#pragma unroll
    for (int i = 0; i < NPB; ++i) { q[i] = 0.f; k[i] = 0.f; v[i] = 0.f; }
    for (int kk = 0; kk < CH; ++kk) {
        float wq = WQ[kk * CH + c], wk = WK[kk * CH + c], wv = WV[kk * CH + c];
#pragma unroll
        for (int i = 0; i < NPB; ++i) {
            q[i] = fmaf(rs[i * CH + kk], wq, q[i]);
            k[i] = fmaf(ss[i * CH + kk], wk, k[i]);
            v[i] = fmaf(ss[i * CH + kk], wv, v[i]);
        }
    }
#pragma unroll
    for (int i = 0; i < NPB; ++i) {
        size_t o = (size_t)(nb + i) * CH + c;
        Qn[o] = q[i]; Kn[o] = k[i]; Vn[o] = v[i];
    }
}

// ---------------- counting sort of edges by dst ------------------------------
__global__ void zero_counts(int* __restrict__ counts)
{
    int i = blockIdx.x * blockDim.x + threadIdx.x;
    if (i < NN) counts[i] = 0;
}

__global__ void hist_kernel(const int* __restrict__ eidx, int* __restrict__ counts)
{
    int e = blockIdx.x * blockDim.x + threadIdx.x;
    if (e < NE) atomicAdd(&counts[eidx[NE + e]], 1);
}

__global__ __launch_bounds__(256) void scan_kernel(
    const int* __restrict__ counts, int* __restrict__ starts, int* __restrict__ cursor)
{
    __shared__ int s[256];
    int tid = threadIdx.x;
    const int CHUNK = (NN + 255) / 256;  // 40
    int base = tid * CHUNK;
    int local = 0;
    for (int i = base; i < base + CHUNK && i < NN; ++i) local += counts[i];
    s[tid] = local;
    __syncthreads();
    for (int off = 1; off < 256; off <<= 1) {
        int t = (tid >= off) ? s[tid - off] : 0;
        __syncthreads();
        s[tid] += t;
        __syncthreads();
    }
    int run = s[tid] - local;  // exclusive prefix for this chunk
    for (int i = base; i < base + CHUNK && i < NN; ++i) {
        starts[i] = run;
        cursor[i] = run;
        run += counts[i];
    }
    if (tid == 255) starts[NN] = s[255];
}

// Emits src in sorted order alongside the permutation.
__global__ void scatter_kernel(const int* __restrict__ eidx,
                               int* __restrict__ cursor, int* __restrict__ perm,
                               int* __restrict__ src_s)
{
    int e = blockIdx.x * blockDim.x + threadIdx.x;
    if (e < NE) {
        int d = eidx[NE + e];
        int p = atomicAdd(&cursor[d], 1);
        perm[p] = e;
        src_s[p] = eidx[e];
    }
}

// ---------------- fully fused: per-node edge loop -----------------------------
// One block (128 thr = channels) per dst node. Edges are dst-sorted, so this
// block owns a contiguous run [starts[n], starts[n+1]).
// Per edge: ec = eattr_row @ WE_col (WE col held in 32 VGPRs), logits via
// 16-lane butterfly, exp, and immediate accumulation of sum(ex) and ex*V.
// No ex buffer is ever materialized (ws stays ~20.6 MB).
__global__ __launch_bounds__(128) void fused_kernel(
    const int* __restrict__ perm, const int* __restrict__ src_s,
    const int* __restrict__ starts, const float* __restrict__ eattr,
    const float* __restrict__ WE, const float* __restrict__ att,
    const float* __restrict__ Qn, const float* __restrict__ Kn,
    const float* __restrict__ Vn, float* __restrict__ out)
{
    int n = blockIdx.x;
    int c = threadIdx.x;
    int start = starts[n], end = starts[n + 1];

    float rWE[BD];                       // WE column c in registers
#pragma unroll
    for (int k = 0; k < BD; ++k) rWE[k] = WE[k * CH + c];
    float a  = att[c];
    float qc = Qn[(size_t)n * CH + c];   // block-constant Q row

    __shared__ float sea[ET * BD];       // 4 KB eattr tile
    __shared__ int s_src[ET];

    float acc = 0.f, sume = 0.f;
    for (int base = start; base < end; base += ET) {
        int m = min(ET, end - base);
        __syncthreads();                 // protect sea/s_src reuse
        if (c < m) s_src[c] = src_s[base + c];
        for (int i = c; i < m * BD; i += 128) {
            int j = i >> 5, k = i & 31;  // row within tile, element in row
            sea[i] = eattr[(size_t)perm[base + j] * BD + k];
        }
        __syncthreads();
        for (int j = 0; j < m; ++j) {
            int src = s_src[j];
            float kv = Kn[(size_t)src * CH + c];
            float vv = Vn[(size_t)src * CH + c];
            float ec0 = 0.f, ec1 = 0.f;
#pragma unroll
            for (int k = 0; k < BD; k += 2) {
                ec0 = fmaf(sea[j * BD + k],     rWE[k],     ec0);
                ec1 = fmaf(sea[j * BD + k + 1], rWE[k + 1], ec1);
            }
            float val = qc + kv + ec0 + ec1;
            val = val > 0.f ? val : NEG * val;
            float t = a * val;
            t += __shfl_xor(t, 1, 16);
            t += __shfl_xor(t, 2, 16);
            t += __shfl_xor(t, 4, 16);
            t += __shfl_xor(t, 8, 16);   // all 16 lanes of head h hold the sum
            float exv = __expf(t);
            sume += exv;
            acc = fmaf(exv, vv, acc);
        }
    }
    out[(size_t)n * CH + c] = (end > start) ? acc / sume : 0.f;
}

extern "C" void kernel_launch(void* const* d_in, const int* in_sizes, int n_in,
                              void* d_out, int out_size, void* d_ws, size_t ws_size,
                              hipStream_t stream)
{
    const float* senders   = (const float*)d_in[0];
    const float* receivers = (const float*)d_in[1];
    const int*   eidx      = (const int*)d_in[2];
    const float* eattr     = (const float*)d_in[3];
    const float* WQ  = (const float*)d_in[4];
    const float* WK  = (const float*)d_in[5];
    const float* WV  = (const float*)d_in[6];
    const float* WE  = (const float*)d_in[7];
    const float* att = (const float*)d_in[8];
    float* out = (float*)d_out;

    char* ws = (char*)d_ws;
    size_t off = 0;
    auto alloc = [&](size_t bytes) -> void* {
        void* p = ws + off;
        off += (bytes + 255) & ~(size_t)255;
        return p;
    };
    // Total ~20.6 MB (round 1 proved >=38.5 MB available; round 2's 43.7 MB NaN'd)
    float* Qn     = (float*)alloc((size_t)NN * CH * 4);
    float* Kn     = (float*)alloc((size_t)NN * CH * 4);
    float* Vn     = (float*)alloc((size_t)NN * CH * 4);
    int*   counts = (int*)alloc((size_t)NN * 4);
    int*   starts = (int*)alloc((size_t)(NN + 1) * 4);
    int*   cursor = (int*)alloc((size_t)NN * 4);
    int*   perm   = (int*)alloc((size_t)NE * 4);
    int*   src_s  = (int*)alloc((size_t)NE * 4);

    zero_counts<<<(NN + 255) / 256, 256, 0, stream>>>(counts);
    hist_kernel<<<(NE + 255) / 256, 256, 0, stream>>>(eidx, counts);
    scan_kernel<<<1, 256, 0, stream>>>(counts, starts, cursor);
    scatter_kernel<<<(NE + 255) / 256, 256, 0, stream>>>(eidx, cursor, perm, src_s);
    proj_kernel<<<NN / NPB, 128, 0, stream>>>(senders, receivers, WQ, WK, WV, Qn, Kn, Vn);
    fused_kernel<<<NN, 128, 0, stream>>>(perm, src_s, starts, eattr, WE, att, Qn, Kn, Vn, out);
}

// Round 4
// 440.644 us; speedup vs baseline: 1.3584x; 1.1746x over previous
//
#include <hip/hip_runtime.h>

#define NN 10000
#define NE 640000
#define CH 128
#define NH 8
#define HD 16
#define BD 32
#define NEG 0.01f

__device__ __forceinline__ float rdlane(float v, int idx) {
    return __int_as_float(__builtin_amdgcn_readlane(__float_as_int(v), idx));
}

// DPP butterfly sum over each 16-lane row (heads are 16 channels): pure VALU,
// no DS-pipe traffic. quad_perm xor1, xor2, then half-mirror + mirror.
template <int CTRL>
__device__ __forceinline__ float dpp_add(float x) {
    int v = __builtin_amdgcn_update_dpp(0, __float_as_int(x), CTRL, 0xF, 0xF, true);
    return x + __int_as_float(v);
}
__device__ __forceinline__ float sum16(float x) {
    x = dpp_add<0xB1>(x);   // quad_perm [1,0,3,2]  (xor 1)
    x = dpp_add<0x4E>(x);   // quad_perm [2,3,0,1]  (xor 2)
    x = dpp_add<0x141>(x);  // row_half_mirror      (crosses quads within 8)
    x = dpp_add<0x140>(x);  // row_mirror           (crosses 8s within 16)
    return x;
}

// ---------------- node projections -> Qn[f32], KVn[float2(K,V)] -------------
// One wave per 4 nodes; lane l owns channels l and l+64. Node x-vectors live
// in VGPRs and are broadcast via v_readlane (no LDS). W loads amortized 4x.
__global__ __launch_bounds__(256) void proj_kernel(
    const float* __restrict__ senders, const float* __restrict__ receivers,
    const float* __restrict__ WQ, const float* __restrict__ WK,
    const float* __restrict__ WV,
    float* __restrict__ Qn, float2* __restrict__ KVn)
{
    int wave = threadIdx.x >> 6, l = threadIdx.x & 63;
    int n0 = (blockIdx.x * 4 + wave) * 4;     // 625 blocks * 4 waves * 4 nodes
    float r0[4], r1[4], s0[4], s1[4];
#pragma unroll
    for (int i = 0; i < 4; ++i) {
        r0[i] = receivers[(size_t)(n0 + i) * CH + l];
        r1[i] = receivers[(size_t)(n0 + i) * CH + 64 + l];
        s0[i] = senders[(size_t)(n0 + i) * CH + l];
        s1[i] = senders[(size_t)(n0 + i) * CH + 64 + l];
    }
    float q0[4] = {0,0,0,0}, q1[4] = {0,0,0,0};
    float k0[4] = {0,0,0,0}, k1[4] = {0,0,0,0};
    float v0[4] = {0,0,0,0}, v1[4] = {0,0,0,0};
#pragma unroll
    for (int half = 0; half < 2; ++half) {
        for (int ln = 0; ln < 64; ++ln) {
            int kk = half * 64 + ln;
            float wq0 = WQ[kk * CH + l], wq1 = WQ[kk * CH + 64 + l];
            float wk0 = WK[kk * CH + l], wk1 = WK[kk * CH + 64 + l];
            float wv0 = WV[kk * CH + l], wv1 = WV[kk * CH + 64 + l];
#pragma unroll
            for (int i = 0; i < 4; ++i) {
                float rv = rdlane(half ? r1[i] : r0[i], ln);
                float sv = rdlane(half ? s1[i] : s0[i], ln);
                q0[i] = fmaf(rv, wq0, q0[i]);  q1[i] = fmaf(rv, wq1, q1[i]);
                k0[i] = fmaf(sv, wk0, k0[i]);  k1[i] = fmaf(sv, wk1, k1[i]);
                v0[i] = fmaf(sv, wv0, v0[i]);  v1[i] = fmaf(sv, wv1, v1[i]);
            }
        }
    }
#pragma unroll
    for (int i = 0; i < 4; ++i) {
        size_t o = (size_t)(n0 + i) * CH;
        Qn[o + l] = q0[i];
        Qn[o + 64 + l] = q1[i];
        KVn[o + l] = make_float2(k0[i], v0[i]);
        KVn[o + 64 + l] = make_float2(k1[i], v1[i]);
    }
}

// ---------------- counting sort of edges by dst ------------------------------
__global__ void zero_counts(int* __restrict__ counts)
{
    int i = blockIdx.x * blockDim.x + threadIdx.x;
    if (i < NN) counts[i] = 0;
}

__global__ void hist_kernel(const int* __restrict__ eidx, int* __restrict__ counts)
{
    int e = blockIdx.x * blockDim.x + threadIdx.x;
    if (e < NE) atomicAdd(&counts[eidx[NE + e]], 1);
}

__global__ __launch_bounds__(1024) void scan_kernel(
    const int* __restrict__ counts, int* __restrict__ starts, int* __restrict__ cursor)
{
    __shared__ int s[1024];
    int tid = threadIdx.x;
    const int CHUNK = 10;  // 1024*10 >= NN
    int base = tid * CHUNK;
    int local = 0;
    for (int i = base; i < base + CHUNK && i < NN; ++i) local += counts[i];
    s[tid] = local;
    __syncthreads();
    for (int off = 1; off < 1024; off <<= 1) {
        int t = (tid >= off) ? s[tid - off] : 0;
        __syncthreads();
        s[tid] += t;
        __syncthreads();
    }
    int run = s[tid] - local;
    for (int i = base; i < base + CHUNK && i < NN; ++i) {
        starts[i] = run;
        cursor[i] = run;
        run += counts[i];
    }
    if (tid == 1023) starts[NN] = s[1023];
}

__global__ void scatter_kernel(const int* __restrict__ eidx,
                               int* __restrict__ cursor, int* __restrict__ perm,
                               int* __restrict__ src_s)
{
    int e = blockIdx.x * blockDim.x + threadIdx.x;
    if (e < NE) {
        int d = eidx[NE + e];
        int p = atomicAdd(&cursor[d], 1);
        perm[p] = e;
        src_s[p] = eidx[e];
    }
}

// ---------------- fused per-node edge loop (one WAVE per node) ---------------
// 256 thr = 4 independent waves, no LDS, no barriers. Lane l owns channels
// l and l+64. Per 4-edge tile: one float2/lane cooperative load covers the 4
// eattr rows (lane group l>>4 = row, (l&15)*2 = float pair); values broadcast
// via v_readlane. KV gathered as float2 from SGPR base. Head reductions via
// DPP (sum16). DS pipe is completely idle in this kernel.
__global__ __launch_bounds__(256) void fused_kernel(
    const int* __restrict__ perm, const int* __restrict__ src_s,
    const int* __restrict__ starts, const float* __restrict__ eattr,
    const float* __restrict__ WE, const float* __restrict__ att,
    const float* __restrict__ Qn, const float2* __restrict__ KVn,
    float* __restrict__ out)
{
    int wave = threadIdx.x >> 6, l = threadIdx.x & 63;
    int n = blockIdx.x * 4 + wave;            // 2500 blocks * 4 waves = NN
    int start = starts[n], end = starts[n + 1];

    float rWE0[BD], rWE1[BD];
#pragma unroll
    for (int k = 0; k < BD; ++k) {
        rWE0[k] = WE[k * CH + l];
        rWE1[k] = WE[k * CH + 64 + l];
    }
    float a0 = att[l], a1 = att[64 + l];
    float q0 = Qn[(size_t)n * CH + l], q1 = Qn[(size_t)n * CH + 64 + l];
    float acc0 = 0.f, acc1 = 0.f, sum0 = 0.f, sum1 = 0.f;

    for (int base = start; base < end; base += 4) {
        int m = min(4, end - base);
        int jrow = min(base + (l >> 4), end - 1);
        int e = perm[jrow];
        float2 sa = *(const float2*)(eattr + (size_t)e * BD + ((l & 15) << 1));
        int vsrc = src_s[min(base + (l & 3), end - 1)];
#pragma unroll 4
        for (int t = 0; t < 4; ++t) {
            if (t >= m) break;                 // uniform
            int src = __builtin_amdgcn_readlane(vsrc, t);
            const float2* kvrow = KVn + (size_t)src * CH;
            float2 kv0 = kvrow[l];
            float2 kv1 = kvrow[64 + l];
            float ec0 = 0.f, ec1 = 0.f;
#pragma unroll
            for (int k = 0; k < BD; k += 2) {
                float se = rdlane(sa.x, t * 16 + (k >> 1));
                float so = rdlane(sa.y, t * 16 + (k >> 1));
                ec0 = fmaf(se, rWE0[k], ec0);
                ec0 = fmaf(so, rWE0[k + 1], ec0);
                ec1 = fmaf(se, rWE1[k], ec1);
                ec1 = fmaf(so, rWE1[k + 1], ec1);
            }
            float h0 = q0 + kv0.x + ec0; h0 = h0 > 0.f ? h0 : NEG * h0;
            float h1 = q1 + kv1.x + ec1; h1 = h1 > 0.f ? h1 : NEG * h1;
            float t0 = sum16(a0 * h0);
            float t1 = sum16(a1 * h1);
            float e0 = __expf(t0), e1 = __expf(t1);
            sum0 += e0; acc0 = fmaf(e0, kv0.y, acc0);
            sum1 += e1; acc1 = fmaf(e1, kv1.y, acc1);
        }
    }
    out[(size_t)n * CH + l]      = (end > start) ? acc0 / sum0 : 0.f;
    out[(size_t)n * CH + 64 + l] = (end > start) ? acc1 / sum1 : 0.f;
}

extern "C" void kernel_launch(void* const* d_in, const int* in_sizes, int n_in,
                              void* d_out, int out_size, void* d_ws, size_t ws_size,
                              hipStream_t stream)
{
    const float* senders   = (const float*)d_in[0];
    const float* receivers = (const float*)d_in[1];
    const int*   eidx      = (const int*)d_in[2];
    const float* eattr     = (const float*)d_in[3];
    const float* WQ  = (const float*)d_in[4];
    const float* WK  = (const float*)d_in[5];
    const float* WV  = (const float*)d_in[6];
    const float* WE  = (const float*)d_in[7];
    const float* att = (const float*)d_in[8];
    float* out = (float*)d_out;

    char* ws = (char*)d_ws;
    size_t off = 0;
    auto alloc = [&](size_t bytes) -> void* {
        void* p = ws + off;
        off += (bytes + 255) & ~(size_t)255;
        return p;
    };
    // Total ~20.6 MB (keep well under the ~40 MB workspace limit found in R2)
    float*  Qn     = (float*)alloc((size_t)NN * CH * 4);
    float2* KVn    = (float2*)alloc((size_t)NN * CH * 8);
    int*    counts = (int*)alloc((size_t)NN * 4);
    int*    starts = (int*)alloc((size_t)(NN + 1) * 4);
    int*    cursor = (int*)alloc((size_t)NN * 4);
    int*    perm   = (int*)alloc((size_t)NE * 4);
    int*    src_s  = (int*)alloc((size_t)NE * 4);

    zero_counts<<<(NN + 255) / 256, 256, 0, stream>>>(counts);
    hist_kernel<<<(NE + 255) / 256, 256, 0, stream>>>(eidx, counts);
    scan_kernel<<<1, 1024, 0, stream>>>(counts, starts, cursor);
    scatter_kernel<<<(NE + 255) / 256, 256, 0, stream>>>(eidx, cursor, perm, src_s);
    proj_kernel<<<NN / 16, 256, 0, stream>>>(senders, receivers, WQ, WK, WV, Qn, KVn);
    fused_kernel<<<NN / 4, 256, 0, stream>>>(perm, src_s, starts, eattr, WE, att, Qn, KVn, out);
}

// Round 5
// 415.749 us; speedup vs baseline: 1.4397x; 1.0599x over previous
//
#include <hip/hip_runtime.h>

#define NN 10000
#define NE 640000
#define CH 128
#define NH 8
#define HD 16
#define BD 32
#define NEG 0.01f

__device__ __forceinline__ float rdlane(float v, int idx) {
    return __int_as_float(__builtin_amdgcn_readlane(__float_as_int(v), idx));
}

// DPP butterfly sum over each 16-lane row (one head = 16 channels): pure VALU.
template <int CTRL>
__device__ __forceinline__ float dpp_add(float x) {
    int v = __builtin_amdgcn_update_dpp(0, __float_as_int(x), CTRL, 0xF, 0xF, true);
    return x + __int_as_float(v);
}
__device__ __forceinline__ float sum16(float x) {
    x = dpp_add<0xB1>(x);   // quad_perm xor1
    x = dpp_add<0x4E>(x);   // quad_perm xor2
    x = dpp_add<0x141>(x);  // row_half_mirror
    x = dpp_add<0x140>(x);  // row_mirror
    return x;
}

// ---------------- node projections -> Qn[f32], KVn[float2(K,V)] -------------
// One wave per 4 nodes; lane l owns channels l and l+64. Node x-vectors in
// VGPRs, broadcast via v_readlane; W loads amortized 4x. Halves split into
// two loops so there is no per-iteration select.
__global__ __launch_bounds__(256) void proj_kernel(
    const float* __restrict__ senders, const float* __restrict__ receivers,
    const float* __restrict__ WQ, const float* __restrict__ WK,
    const float* __restrict__ WV,
    float* __restrict__ Qn, float2* __restrict__ KVn)
{
    int wave = threadIdx.x >> 6, l = threadIdx.x & 63;
    int n0 = (blockIdx.x * 4 + wave) * 4;     // 625 blocks * 4 waves * 4 nodes
    float r0[4], r1[4], s0[4], s1[4];
#pragma unroll
    for (int i = 0; i < 4; ++i) {
        r0[i] = receivers[(size_t)(n0 + i) * CH + l];
        r1[i] = receivers[(size_t)(n0 + i) * CH + 64 + l];
        s0[i] = senders[(size_t)(n0 + i) * CH + l];
        s1[i] = senders[(size_t)(n0 + i) * CH + 64 + l];
    }
    float q0[4] = {0,0,0,0}, q1[4] = {0,0,0,0};
    float k0[4] = {0,0,0,0}, k1[4] = {0,0,0,0};
    float v0[4] = {0,0,0,0}, v1[4] = {0,0,0,0};
    for (int ln = 0; ln < 64; ++ln) {
        float wq0 = WQ[ln * CH + l], wq1 = WQ[ln * CH + 64 + l];
        float wk0 = WK[ln * CH + l], wk1 = WK[ln * CH + 64 + l];
        float wv0 = WV[ln * CH + l], wv1 = WV[ln * CH + 64 + l];
#pragma unroll
        for (int i = 0; i < 4; ++i) {
            float rv = rdlane(r0[i], ln);
            float sv = rdlane(s0[i], ln);
            q0[i] = fmaf(rv, wq0, q0[i]);  q1[i] = fmaf(rv, wq1, q1[i]);
            k0[i] = fmaf(sv, wk0, k0[i]);  k1[i] = fmaf(sv, wk1, k1[i]);
            v0[i] = fmaf(sv, wv0, v0[i]);  v1[i] = fmaf(sv, wv1, v1[i]);
        }
    }
    for (int ln = 0; ln < 64; ++ln) {
        int kk = 64 + ln;
        float wq0 = WQ[kk * CH + l], wq1 = WQ[kk * CH + 64 + l];
        float wk0 = WK[kk * CH + l], wk1 = WK[kk * CH + 64 + l];
        float wv0 = WV[kk * CH + l], wv1 = WV[kk * CH + 64 + l];
#pragma unroll
        for (int i = 0; i < 4; ++i) {
            float rv = rdlane(r1[i], ln);
            float sv = rdlane(s1[i], ln);
            q0[i] = fmaf(rv, wq0, q0[i]);  q1[i] = fmaf(rv, wq1, q1[i]);
            k0[i] = fmaf(sv, wk0, k0[i]);  k1[i] = fmaf(sv, wk1, k1[i]);
            v0[i] = fmaf(sv, wv0, v0[i]);  v1[i] = fmaf(sv, wv1, v1[i]);
        }
    }
#pragma unroll
    for (int i = 0; i < 4; ++i) {
        size_t o = (size_t)(n0 + i) * CH;
        Qn[o + l] = q0[i];
        Qn[o + 64 + l] = q1[i];
        KVn[o + l] = make_float2(k0[i], v0[i]);
        KVn[o + 64 + l] = make_float2(k1[i], v1[i]);
    }
}

// ---------------- counting sort of edges by dst (atomic-free scatter) --------
__global__ void zero_counts(int* __restrict__ counts)
{
    int i = blockIdx.x * blockDim.x + threadIdx.x;
    if (i < NN) counts[i] = 0;
}

// Histogram AND per-edge rank within its bucket in one pass.
__global__ void hist_kernel(const int* __restrict__ eidx, int* __restrict__ counts,
                            int* __restrict__ rank)
{
    int e = blockIdx.x * blockDim.x + threadIdx.x;
    if (e < NE) rank[e] = atomicAdd(&counts[eidx[NE + e]], 1);
}

__global__ __launch_bounds__(1024) void scan_kernel(
    const int* __restrict__ counts, int* __restrict__ starts)
{
    __shared__ int s[1024];
    int tid = threadIdx.x;
    const int CHUNK = 10;  // 1024*10 >= NN
    int base = tid * CHUNK;
    int local = 0;
    for (int i = base; i < base + CHUNK && i < NN; ++i) local += counts[i];
    s[tid] = local;
    __syncthreads();
    for (int off = 1; off < 1024; off <<= 1) {
        int t = (tid >= off) ? s[tid - off] : 0;
        __syncthreads();
        s[tid] += t;
        __syncthreads();
    }
    int run = s[tid] - local;
    for (int i = base; i < base + CHUNK && i < NN; ++i) {
        starts[i] = run;
        run += counts[i];
    }
    if (tid == 1023) starts[NN] = s[1023];
}

__global__ void scatter_kernel(const int* __restrict__ eidx,
                               const int* __restrict__ rank,
                               const int* __restrict__ starts,
                               int* __restrict__ perm, int* __restrict__ src_s)
{
    int e = blockIdx.x * blockDim.x + threadIdx.x;
    if (e < NE) {
        int p = starts[eidx[NE + e]] + rank[e];
        perm[p] = e;
        src_s[p] = eidx[e];
    }
}

// ---------------- fused per-node edge loop ----------------------------------
// One WAVE per (node, 64-channel half): 20000 waves, no LDS, no barriers.
// rWE is 32 VGPRs (fits - the R4 version's 64 didn't, and the compiler
// re-loaded WE per edge). All wave-uniform data (perm, src, eattr rows) is
// pulled through readfirstlane so it lives in SGPRs via s_load: the E-proj
// is 32 v_fmac(v,s,v), zero readlanes, zero per-edge WE traffic.
__global__ __launch_bounds__(256) void fused_kernel(
    const int* __restrict__ perm, const int* __restrict__ src_s,
    const int* __restrict__ starts, const float* __restrict__ eattr,
    const float* __restrict__ WE, const float* __restrict__ att,
    const float* __restrict__ Qn, const float2* __restrict__ KVn,
    float* __restrict__ out)
{
    int wave = threadIdx.x >> 6, l = threadIdx.x & 63;
    int n = blockIdx.x * 2 + (wave >> 1);     // 5000 blocks * 2 nodes
    int coff = (wave & 1) << 6;               // channel half
    int c = coff + l;
    int start = starts[n], end = starts[n + 1];

    float rWE[BD];
#pragma unroll
    for (int k = 0; k < BD; ++k) rWE[k] = WE[k * CH + c];
    float a = att[c];
    float q = Qn[(size_t)n * CH + c];
    float acc = 0.f, sume = 0.f;

    for (int base = start; base < end; base += 4) {
        int m = min(4, end - base);
#pragma unroll 4
        for (int t = 0; t < 4; ++t) {
            if (t >= m) break;                 // uniform
            int e   = __builtin_amdgcn_readfirstlane(perm[base + t]);
            int src = __builtin_amdgcn_readfirstlane(src_s[base + t]);
            const float* __restrict__ row = eattr + (size_t)e * BD;
            float2 kv = KVn[(size_t)src * CH + c];
            float ec0 = 0.f, ec1 = 0.f;
#pragma unroll
            for (int k = 0; k < BD; k += 2) {
                ec0 = fmaf(row[k],     rWE[k],     ec0);
                ec1 = fmaf(row[k + 1], rWE[k + 1], ec1);
            }
            float h = q + kv.x + ec0 + ec1;
            h = h > 0.f ? h : NEG * h;
            float t0 = sum16(a * h);
            float e0 = __expf(t0);
            sume += e0;
            acc = fmaf(e0, kv.y, acc);
        }
    }
    out[(size_t)n * CH + c] = (end > start) ? acc / sume : 0.f;
}

extern "C" void kernel_launch(void* const* d_in, const int* in_sizes, int n_in,
                              void* d_out, int out_size, void* d_ws, size_t ws_size,
                              hipStream_t stream)
{
    const float* senders   = (const float*)d_in[0];
    const float* receivers = (const float*)d_in[1];
    const int*   eidx      = (const int*)d_in[2];
    const float* eattr     = (const float*)d_in[3];
    const float* WQ  = (const float*)d_in[4];
    const float* WK  = (const float*)d_in[5];
    const float* WV  = (const float*)d_in[6];
    const float* WE  = (const float*)d_in[7];
    const float* att = (const float*)d_in[8];
    float* out = (float*)d_out;

    char* ws = (char*)d_ws;
    size_t off = 0;
    auto alloc = [&](size_t bytes) -> void* {
        void* p = ws + off;
        off += (bytes + 255) & ~(size_t)255;
        return p;
    };
    // Total ~23.2 MB (< 38.5 MB proven safe in R1; R2's 43.7 MB failed)
    float*  Qn     = (float*)alloc((size_t)NN * CH * 4);
    float2* KVn    = (float2*)alloc((size_t)NN * CH * 8);
    int*    counts = (int*)alloc((size_t)NN * 4);
    int*    starts = (int*)alloc((size_t)(NN + 1) * 4);
    int*    rank   = (int*)alloc((size_t)NE * 4);
    int*    perm   = (int*)alloc((size_t)NE * 4);
    int*    src_s  = (int*)alloc((size_t)NE * 4);

    zero_counts<<<(NN + 255) / 256, 256, 0, stream>>>(counts);
    hist_kernel<<<(NE + 255) / 256, 256, 0, stream>>>(eidx, counts, rank);
    scan_kernel<<<1, 1024, 0, stream>>>(counts, starts);
    scatter_kernel<<<(NE + 255) / 256, 256, 0, stream>>>(eidx, rank, starts, perm, src_s);
    proj_kernel<<<NN / 16, 256, 0, stream>>>(senders, receivers, WQ, WK, WV, Qn, KVn);
    fused_kernel<<<NN / 2, 256, 0, stream>>>(perm, src_s, starts, eattr, WE, att, Qn, KVn, out);
}

// Round 6
// 363.597 us; speedup vs baseline: 1.6462x; 1.1434x over previous
//
#include <hip/hip_runtime.h>

#define NN 10000
#define NE 640000
#define CH 128
#define NH 8
#define HD 16
#define BD 32
#define NEG 0.01f

__device__ __forceinline__ float rdlane(float v, int idx) {
    return __int_as_float(__builtin_amdgcn_readlane(__float_as_int(v), idx));
}

// DPP butterfly sum over each 16-lane row (one head = 16 channels): pure VALU.
template <int CTRL>
__device__ __forceinline__ float dpp_add(float x) {
    int v = __builtin_amdgcn_update_dpp(0, __float_as_int(x), CTRL, 0xF, 0xF, true);
    return x + __int_as_float(v);
}
__device__ __forceinline__ float sum16(float x) {
    x = dpp_add<0xB1>(x);   // quad_perm xor1
    x = dpp_add<0x4E>(x);   // quad_perm xor2
    x = dpp_add<0x141>(x);  // row_half_mirror
    x = dpp_add<0x140>(x);  // row_mirror
    return x;
}

// ---------------- node projections -> Qn[f32], KVn[float2(K,V)] -------------
__global__ __launch_bounds__(256) void proj_kernel(
    const float* __restrict__ senders, const float* __restrict__ receivers,
    const float* __restrict__ WQ, const float* __restrict__ WK,
    const float* __restrict__ WV,
    float* __restrict__ Qn, float2* __restrict__ KVn)
{
    int wave = threadIdx.x >> 6, l = threadIdx.x & 63;
    int n0 = (blockIdx.x * 4 + wave) * 4;     // 625 blocks * 4 waves * 4 nodes
    float r0[4], r1[4], s0[4], s1[4];
#pragma unroll
    for (int i = 0; i < 4; ++i) {
        r0[i] = receivers[(size_t)(n0 + i) * CH + l];
        r1[i] = receivers[(size_t)(n0 + i) * CH + 64 + l];
        s0[i] = senders[(size_t)(n0 + i) * CH + l];
        s1[i] = senders[(size_t)(n0 + i) * CH + 64 + l];
    }
    float q0[4] = {0,0,0,0}, q1[4] = {0,0,0,0};
    float k0[4] = {0,0,0,0}, k1[4] = {0,0,0,0};
    float v0[4] = {0,0,0,0}, v1[4] = {0,0,0,0};
    for (int ln = 0; ln < 64; ++ln) {
        float wq0 = WQ[ln * CH + l], wq1 = WQ[ln * CH + 64 + l];
        float wk0 = WK[ln * CH + l], wk1 = WK[ln * CH + 64 + l];
        float wv0 = WV[ln * CH + l], wv1 = WV[ln * CH + 64 + l];
#pragma unroll
        for (int i = 0; i < 4; ++i) {
            float rv = rdlane(r0[i], ln);
            float sv = rdlane(s0[i], ln);
            q0[i] = fmaf(rv, wq0, q0[i]);  q1[i] = fmaf(rv, wq1, q1[i]);
            k0[i] = fmaf(sv, wk0, k0[i]);  k1[i] = fmaf(sv, wk1, k1[i]);
            v0[i] = fmaf(sv, wv0, v0[i]);  v1[i] = fmaf(sv, wv1, v1[i]);
        }
    }
    for (int ln = 0; ln < 64; ++ln) {
        int kk = 64 + ln;
        float wq0 = WQ[kk * CH + l], wq1 = WQ[kk * CH + 64 + l];
        float wk0 = WK[kk * CH + l], wk1 = WK[kk * CH + 64 + l];
        float wv0 = WV[kk * CH + l], wv1 = WV[kk * CH + 64 + l];
#pragma unroll
        for (int i = 0; i < 4; ++i) {
            float rv = rdlane(r1[i], ln);
            float sv = rdlane(s1[i], ln);
            q0[i] = fmaf(rv, wq0, q0[i]);  q1[i] = fmaf(rv, wq1, q1[i]);
            k0[i] = fmaf(sv, wk0, k0[i]);  k1[i] = fmaf(sv, wk1, k1[i]);
            v0[i] = fmaf(sv, wv0, v0[i]);  v1[i] = fmaf(sv, wv1, v1[i]);
        }
    }
#pragma unroll
    for (int i = 0; i < 4; ++i) {
        size_t o = (size_t)(n0 + i) * CH;
        Qn[o + l] = q0[i];
        Qn[o + 64 + l] = q1[i];
        KVn[o + l] = make_float2(k0[i], v0[i]);
        KVn[o + 64 + l] = make_float2(k1[i], v1[i]);
    }
}

// ---------------- counting sort of edges by dst (atomic-free scatter) --------
__global__ void zero_counts(int* __restrict__ counts)
{
    int i = blockIdx.x * blockDim.x + threadIdx.x;
    if (i < NN) counts[i] = 0;
}

__global__ void hist_kernel(const int* __restrict__ eidx, int* __restrict__ counts,
                            int* __restrict__ rank)
{
    int e = blockIdx.x * blockDim.x + threadIdx.x;
    if (e < NE) rank[e] = atomicAdd(&counts[eidx[NE + e]], 1);
}

__global__ __launch_bounds__(1024) void scan_kernel(
    const int* __restrict__ counts, int* __restrict__ starts)
{
    __shared__ int s[1024];
    int tid = threadIdx.x;
    const int CHUNK = 10;  // 1024*10 >= NN
    int base = tid * CHUNK;
    int local = 0;
    for (int i = base; i < base + CHUNK && i < NN; ++i) local += counts[i];
    s[tid] = local;
    __syncthreads();
    for (int off = 1; off < 1024; off <<= 1) {
        int t = (tid >= off) ? s[tid - off] : 0;
        __syncthreads();
        s[tid] += t;
        __syncthreads();
    }
    int run = s[tid] - local;
    for (int i = base; i < base + CHUNK && i < NN; ++i) {
        starts[i] = run;
        run += counts[i];
    }
    if (tid == 1023) starts[NN] = s[1023];
}

__global__ void scatter_kernel(const int* __restrict__ eidx,
                               const int* __restrict__ rank,
                               const int* __restrict__ starts,
                               int* __restrict__ perm, int* __restrict__ src_s)
{
    int e = blockIdx.x * blockDim.x + threadIdx.x;
    if (e < NE) {
        int p = starts[eidx[NE + e]] + rank[e];
        perm[p] = e;
        src_s[p] = eidx[e];
    }
}

// ---------------- fused per-node edge loop ----------------------------------
// One WAVE per node, lane l owns channels l and l+64. rWE[64] is force-pinned
// into VGPRs via empty "+v" asm (R4/R5 showed the compiler otherwise sinks
// the WE loads into the edge loop: VGPR_Count 48 then 28). launch_bounds
// (256,4) gives the allocator a 128-VGPR budget for it. 8-edge tiles: lanes
// 0..7 load perm/src coalesced, readlane-broadcast per edge; eattr rows are
// uniform s_loads (each row fetched ONCE per edge now, not once per half).
__global__ __launch_bounds__(256, 4) void fused_kernel(
    const int* __restrict__ perm, const int* __restrict__ src_s,
    const int* __restrict__ starts, const float* __restrict__ eattr,
    const float* __restrict__ WE, const float* __restrict__ att,
    const float* __restrict__ Qn, const float2* __restrict__ KVn,
    float* __restrict__ out)
{
    int wave = threadIdx.x >> 6, l = threadIdx.x & 63;
    int n = blockIdx.x * 4 + wave;            // 2500 blocks * 4 waves = NN
    int start = starts[n], end = starts[n + 1];

    float rWE[2 * BD];
#pragma unroll
    for (int k = 0; k < BD; ++k) {
        rWE[k]      = WE[k * CH + l];
        rWE[BD + k] = WE[k * CH + 64 + l];
    }
#pragma unroll
    for (int k = 0; k < 2 * BD; ++k) asm volatile("" : "+v"(rWE[k]));

    float a0 = att[l], a1 = att[64 + l];
    float q0 = Qn[(size_t)n * CH + l], q1 = Qn[(size_t)n * CH + 64 + l];
    float acc0 = 0.f, acc1 = 0.f, sum0 = 0.f, sum1 = 0.f;

    for (int base = start; base < end; base += 8) {
        int m = end - base;                   // >=1
        int idx = base + (l & 7);
        if (idx >= end) idx = end - 1;
        int vperm = perm[idx];
        int vsrc  = src_s[idx];
#pragma unroll 8
        for (int t = 0; t < 8; ++t) {
            if (t >= m) break;                // wave-uniform
            int e   = __builtin_amdgcn_readlane(vperm, t);
            int src = __builtin_amdgcn_readlane(vsrc, t);
            const float* __restrict__ row = eattr + (size_t)e * BD;
            const float2* __restrict__ kvrow = KVn + (size_t)src * CH;
            float2 kv0 = kvrow[l];
            float2 kv1 = kvrow[64 + l];
            float ec0 = 0.f, ec1 = 0.f;
#pragma unroll
            for (int k = 0; k < BD; ++k) {
                float rv = row[k];            // uniform -> s_load
                ec0 = fmaf(rv, rWE[k],      ec0);
                ec1 = fmaf(rv, rWE[BD + k], ec1);
            }
            float h0 = q0 + kv0.x + ec0; h0 = h0 > 0.f ? h0 : NEG * h0;
            float h1 = q1 + kv1.x + ec1; h1 = h1 > 0.f ? h1 : NEG * h1;
            float t0 = sum16(a0 * h0);
            float t1 = sum16(a1 * h1);
            float e0 = __expf(t0), e1 = __expf(t1);
            sum0 += e0; acc0 = fmaf(e0, kv0.y, acc0);
            sum1 += e1; acc1 = fmaf(e1, kv1.y, acc1);
        }
    }
    out[(size_t)n * CH + l]      = (end > start) ? acc0 / sum0 : 0.f;
    out[(size_t)n * CH + 64 + l] = (end > start) ? acc1 / sum1 : 0.f;
}

extern "C" void kernel_launch(void* const* d_in, const int* in_sizes, int n_in,
                              void* d_out, int out_size, void* d_ws, size_t ws_size,
                              hipStream_t stream)
{
    const float* senders   = (const float*)d_in[0];
    const float* receivers = (const float*)d_in[1];
    const int*   eidx      = (const int*)d_in[2];
    const float* eattr     = (const float*)d_in[3];
    const float* WQ  = (const float*)d_in[4];
    const float* WK  = (const float*)d_in[5];
    const float* WV  = (const float*)d_in[6];
    const float* WE  = (const float*)d_in[7];
    const float* att = (const float*)d_in[8];
    float* out = (float*)d_out;

    char* ws = (char*)d_ws;
    size_t off = 0;
    auto alloc = [&](size_t bytes) -> void* {
        void* p = ws + off;
        off += (bytes + 255) & ~(size_t)255;
        return p;
    };
    // Total ~23.2 MB (< 38.5 MB proven safe in R1; R2's 43.7 MB failed)
    float*  Qn     = (float*)alloc((size_t)NN * CH * 4);
    float2* KVn    = (float2*)alloc((size_t)NN * CH * 8);
    int*    counts = (int*)alloc((size_t)NN * 4);
    int*    starts = (int*)alloc((size_t)(NN + 1) * 4);
    int*    rank   = (int*)alloc((size_t)NE * 4);
    int*    perm   = (int*)alloc((size_t)NE * 4);
    int*    src_s  = (int*)alloc((size_t)NE * 4);

    zero_counts<<<(NN + 255) / 256, 256, 0, stream>>>(counts);
    hist_kernel<<<(NE + 255) / 256, 256, 0, stream>>>(eidx, counts, rank);
    scan_kernel<<<1, 1024, 0, stream>>>(counts, starts);
    scatter_kernel<<<(NE + 255) / 256, 256, 0, stream>>>(eidx, rank, starts, perm, src_s);
    proj_kernel<<<NN / 16, 256, 0, stream>>>(senders, receivers, WQ, WK, WV, Qn, KVn);
    fused_kernel<<<NN / 4, 256, 0, stream>>>(perm, src_s, starts, eattr, WE, att, Qn, KVn, out);
}